// Round 7
// baseline (506.163 us; speedup 1.0000x reference)
//
#include <hip/hip_runtime.h>
#include <hip/hip_bf16.h>

#define D 64
#define RPB 16                  // rows per bucket (4-bit local row)
#define NPART 8                 // per-XCD stream partitions (blockIdx & 7)
#define SORT_CAP 2048           // LDS staging capacity (recs) for in-place bucket sort
#define SCAN_BLOCK 256

typedef unsigned long long ull;

// ---------------- fallback: round-1 atomic kernel ----------------
__global__ __launch_bounds__(256) void spmm_atomic_kernel(
    const float* __restrict__ x,
    const int*   __restrict__ edge_row,
    const int*   __restrict__ edge_col,
    const float* __restrict__ edge_val,
    float*       __restrict__ out,
    int n_edges)
{
    const int gtid = blockIdx.x * blockDim.x + threadIdx.x;
    const int wave = gtid >> 6;
    const int lane = threadIdx.x & 63;
    if (wave >= n_edges) return;
    const int   r = edge_row[wave];
    const int   c = edge_col[wave];
    const float v = edge_val[wave];
    atomicAdd(&out[(size_t)r * D + lane], v * x[(size_t)c * D + lane]);
}

// ---------------- (bucket, partition) histogram ----------------
// Counters padded to `pad` ints each (pad=32 -> one 128B line per counter):
// device-scope atomics serialize PER CACHE LINE at the coherence point
// (round-6 evidence: 2048 atomics/line -> 66 ns each -> 136 us).
__global__ void hist_kernel(const int* __restrict__ rows,
                            int* __restrict__ counts_pm,
                            int n_edges, int n_buckets, int pad)
{
    const int i = blockIdx.x * blockDim.x + threadIdx.x;
    const int p = blockIdx.x & (NPART - 1);
    if (i < n_edges)
        atomicAdd(&counts_pm[(p * n_buckets + (rows[i] >> 4)) * pad], 1);
}

// ---------------- blocked exclusive scan over keys k = bucket*8 + p ----------------
// reads padded counts permuted (partition-major), writes bucket-major bp_offsets
// and (in-place, padded) the cursor for the scatter.
__global__ void scan_partial_kernel(const int* __restrict__ counts_pm,
                                    int* __restrict__ partials,
                                    int nscan, int n_buckets, int pad)
{
    __shared__ int s[SCAN_BLOCK];
    const int k = blockIdx.x * SCAN_BLOCK + threadIdx.x;
    int v = 0;
    if (k < n_buckets * NPART)
        v = counts_pm[((k & (NPART - 1)) * n_buckets + (k >> 3)) * pad];
    s[threadIdx.x] = v;
    __syncthreads();
    for (int off = SCAN_BLOCK / 2; off > 0; off >>= 1) {
        if (threadIdx.x < off) s[threadIdx.x] += s[threadIdx.x + off];
        __syncthreads();
    }
    if (threadIdx.x == 0) partials[blockIdx.x] = s[0];
}

__global__ __launch_bounds__(1024) void scan_top_kernel(int* partials, int nparts)
{
    __shared__ int s[1024];
    int t = threadIdx.x;
    int mine = (t < nparts) ? partials[t] : 0;
    s[t] = mine;
    for (int off = 1; off < 1024; off <<= 1) {
        __syncthreads();
        int v = (t >= off) ? s[t - off] : 0;
        __syncthreads();
        s[t] += v;
    }
    if (t < nparts) partials[t] = s[t] - mine;  // exclusive
}

// counts -> exclusive offsets; cursor written in place of counts (padded slot)
__global__ void scan_final_kernel(int* __restrict__ counts_cursor_pm,
                                  const int* __restrict__ partials,
                                  int* __restrict__ bp_offsets,   // [n_buckets*8 + 1]
                                  int nscan, int n_buckets, int pad)
{
    __shared__ int s[SCAN_BLOCK];
    const int t = threadIdx.x;
    const int k = blockIdx.x * SCAN_BLOCK + t;
    int idx = -1, mine = 0;
    if (k < n_buckets * NPART) {
        idx  = ((k & (NPART - 1)) * n_buckets + (k >> 3)) * pad;
        mine = counts_cursor_pm[idx];
    }
    s[t] = mine;
    for (int off = 1; off < SCAN_BLOCK; off <<= 1) {
        __syncthreads();
        int v = (t >= off) ? s[t - off] : 0;
        __syncthreads();
        s[t] += v;
    }
    const int excl = s[t] - mine + partials[blockIdx.x];
    if (k < nscan) {
        bp_offsets[k] = excl;
        if (idx >= 0) counts_cursor_pm[idx] = excl;   // becomes the scatter cursor
    }
}

// ---------------- scatter edges into XCD-local bucket streams ----------------
// rec = [ val:f32 (hi32) | localrow:bits17-20 | col:bits0-16 (lo32) ]
// Same grid geometry + same p = blockIdx&7 as hist_kernel -> counts match exactly.
__global__ void scatter_kernel(const int* __restrict__ rows,
                               const int* __restrict__ cols,
                               const float* __restrict__ vals,
                               int* __restrict__ cursor_pm,
                               ull* __restrict__ recs,
                               int n_edges, int n_buckets, int pad)
{
    const int i = blockIdx.x * blockDim.x + threadIdx.x;
    const int p = blockIdx.x & (NPART - 1);
    if (i >= n_edges) return;
    const int   r = rows[i];
    const int   c = cols[i];
    const float v = vals[i];
    const unsigned lo = ((unsigned)(r & (RPB - 1)) << 17) | (unsigned)c;
    const int pos = atomicAdd(&cursor_pm[(p * n_buckets + (r >> 4)) * pad], 1);
    recs[pos] = ((ull)__float_as_uint(v) << 32) | (ull)lo;
}

// ---------------- in-place within-bucket sort + row-offset emission ----------------
__global__ __launch_bounds__(256) void bucket_sort_kernel(
    ull* __restrict__ recs,
    const int* __restrict__ bp_offsets,
    int* __restrict__ offsets_row,   // [n_nodes + 1]
    int* __restrict__ flags,
    int n_buckets, int n_nodes)
{
    __shared__ ull stage[SORT_CAP];
    __shared__ int cnt[RPB];
    __shared__ int cur[RPB];
    const int b = blockIdx.x;
    const int t = threadIdx.x;

    const int seg0 = bp_offsets[b * NPART];
    const int seg1 = bp_offsets[b * NPART + NPART];
    const int len  = seg1 - seg0;

    if (len > SORT_CAP) {            // ~infeasible for uniform data; leave unsorted
        if (t == 0) flags[b] = 1;
        return;
    }
    if (t < RPB) cnt[t] = 0;
    __syncthreads();

    // stage + local row histogram
    for (int i = t; i < len; i += 256) {
        const ull rr = recs[seg0 + i];
        stage[i] = rr;
        atomicAdd(&cnt[(int)((rr >> 17) & (RPB - 1))], 1);
    }
    __syncthreads();

    if (t == 0) {
        int s = 0;
        #pragma unroll
        for (int k = 0; k < RPB; ++k) { cur[k] = s; s += cnt[k]; }
    }
    __syncthreads();

    // emit global row offsets (sentinel r0+RPB duplicated by neighbor — benign)
    const int r0 = b * RPB;
    if (t <= RPB) {
        const int r = r0 + t;
        if (r <= n_nodes)
            offsets_row[r] = seg0 + ((t == RPB) ? len : cur[t]);
    }
    __syncthreads();

    // permute to full row order
    for (int i = t; i < len; i += 256) {
        const ull rr = stage[i];
        const int lr = (int)((rr >> 17) & (RPB - 1));
        const int p  = atomicAdd(&cur[lr], 1);
        recs[seg0 + p] = rr;
    }
}

// ---------------- CSR SpMM: one wave per row, lane = feature ----------------
__global__ __launch_bounds__(256) void spmm_csr_kernel(
    const float* __restrict__ x,
    const int*   __restrict__ offsets_row,
    const int*   __restrict__ bp_offsets,
    const ull*   __restrict__ recs,
    const int*   __restrict__ flags,
    float*       __restrict__ out,
    int n_nodes)
{
    const int row  = blockIdx.x * 4 + (threadIdx.x >> 6);
    const int lane = threadIdx.x & 63;
    if (row >= n_nodes) return;

    float acc = 0.f;
    const int b = row >> 4;

    if (__builtin_expect(flags[b], 0)) {
        // safety path: bucket left unsorted — scan whole bucket, filter my row
        const int s  = bp_offsets[b * NPART];
        const int e  = bp_offsets[b * NPART + NPART];
        const int lr = row & (RPB - 1);
        for (int j = s; j < e; ++j) {
            const ull rec = recs[j];
            if ((int)((rec >> 17) & (RPB - 1)) == lr) {
                const int   c = (int)((unsigned)rec & 0x1FFFF);
                const float v = __uint_as_float((unsigned)(rec >> 32));
                acc += v * x[(size_t)c * D + lane];
            }
        }
    } else {
        const int s = offsets_row[row];
        const int e = offsets_row[row + 1];
        int j = s;
        for (; j + 8 <= e; j += 8) {
            float vv[8], xv[8];
            #pragma unroll
            for (int k = 0; k < 8; ++k) {
                const ull rec = recs[j + k];
                vv[k] = __uint_as_float((unsigned)(rec >> 32));
                const int c = (int)((unsigned)rec & 0x1FFFF);
                xv[k] = x[(size_t)c * D + lane];
            }
            #pragma unroll
            for (int k = 0; k < 8; ++k) acc += vv[k] * xv[k];
        }
        for (; j < e; ++j) {
            const ull rec = recs[j];
            const float v = __uint_as_float((unsigned)(rec >> 32));
            const int   c = (int)((unsigned)rec & 0x1FFFF);
            acc += v * x[(size_t)c * D + lane];
        }
    }
    out[(size_t)row * D + lane] = acc;
}

static inline size_t align16(size_t v) { return (v + 15) & ~(size_t)15; }

extern "C" void kernel_launch(void* const* d_in, const int* in_sizes, int n_in,
                              void* d_out, int out_size, void* d_ws, size_t ws_size,
                              hipStream_t stream)
{
    // setup_inputs order: t, x, edge_row, edge_col, edge_val
    const float* x        = (const float*)d_in[1];
    const int*   edge_row = (const int*)d_in[2];
    const int*   edge_col = (const int*)d_in[3];
    const float* edge_val = (const float*)d_in[4];
    float*       out      = (float*)d_out;

    const int n_edges   = in_sizes[2];
    const int n_nodes   = out_size / D;
    const int n_buckets = (n_nodes + RPB - 1) / RPB;
    const int nscan     = n_buckets * NPART + 1;
    const int nparts    = (nscan + SCAN_BLOCK - 1) / SCAN_BLOCK;

    // choose counter padding: 32 ints = one 128B line per counter if ws allows
    int pad = 1;
    size_t ws_needed = 0;
    size_t off_recs = 0, off_counts = 0, off_bpoffs = 0, off_rowoffs = 0,
           off_flags = 0, off_parts = 0;
    for (int try_pad = 32; try_pad >= 1; try_pad >>= 1) {
        off_recs    = 0;
        off_counts  = align16(off_recs + (size_t)n_edges * 8);
        off_bpoffs  = align16(off_counts + (size_t)n_buckets * NPART * try_pad * 4);
        off_rowoffs = align16(off_bpoffs + (size_t)nscan * 4);
        off_flags   = align16(off_rowoffs + (size_t)(n_nodes + 1) * 4);
        off_parts   = align16(off_flags + (size_t)n_buckets * 4);
        ws_needed   = off_parts + 1024 * 4;
        pad = try_pad;
        if (ws_needed <= ws_size) break;
    }

    if (ws_size < ws_needed || nparts > 1024 || n_nodes > (1 << 17)) {
        hipMemsetAsync(out, 0, (size_t)out_size * sizeof(float), stream);
        const int n_blocks = (n_edges + 3) / 4;
        spmm_atomic_kernel<<<n_blocks, 256, 0, stream>>>(
            x, edge_row, edge_col, edge_val, out, n_edges);
        return;
    }

    char* ws = (char*)d_ws;
    ull*  recs        = (ull*)(ws + off_recs);
    int*  counts_pm   = (int*)(ws + off_counts);   // also the cursor after scan
    int*  bp_offsets  = (int*)(ws + off_bpoffs);
    int*  offsets_row = (int*)(ws + off_rowoffs);
    int*  flags       = (int*)(ws + off_flags);
    int*  parts       = (int*)(ws + off_parts);

    // 1. zero counters + flags
    hipMemsetAsync(counts_pm, 0, (size_t)n_buckets * NPART * pad * sizeof(int), stream);
    hipMemsetAsync(flags, 0, (size_t)n_buckets * sizeof(int), stream);

    // 2. (bucket, partition) histogram — line-padded counters
    const int eb = (n_edges + 255) / 256;
    hist_kernel<<<eb, 256, 0, stream>>>(edge_row, counts_pm, n_edges, n_buckets, pad);

    // 3. exclusive scan over (bucket, partition) keys
    scan_partial_kernel<<<nparts, SCAN_BLOCK, 0, stream>>>(
        counts_pm, parts, nscan, n_buckets, pad);
    scan_top_kernel<<<1, 1024, 0, stream>>>(parts, nparts);
    scan_final_kernel<<<nparts, SCAN_BLOCK, 0, stream>>>(
        counts_pm, parts, bp_offsets, nscan, n_buckets, pad);

    // 4. scatter into XCD-local bucket streams — line-padded cursors
    scatter_kernel<<<eb, 256, 0, stream>>>(edge_row, edge_col, edge_val,
                                           counts_pm, recs, n_edges, n_buckets, pad);

    // 5. in-place within-bucket sort -> full row order + row offsets
    bucket_sort_kernel<<<n_buckets, 256, 0, stream>>>(
        recs, bp_offsets, offsets_row, flags, n_buckets, n_nodes);

    // 6. CSR SpMM: one wave per row (max TLP shape — 100k waves)
    spmm_csr_kernel<<<(n_nodes + 3) / 4, 256, 0, stream>>>(
        x, offsets_row, bp_offsets, recs, flags, out, n_nodes);
}

// Round 8
// 313.353 us; speedup vs baseline: 1.6153x; 1.6153x over previous
//
#include <hip/hip_runtime.h>
#include <hip/hip_bf16.h>

#define D 64
#define RB 128            // rows per bin (7-bit local row)
#define NB_MAX 1024       // max bins (n_nodes <= 2^17)
#define NBLK 256          // blocks for count/scatter passes (must match!)
#define CAP 5120          // K5 LDS staging capacity (records) = 40 KB

typedef unsigned long long ull;

// ---------------- fallback: round-1 atomic kernel ----------------
__global__ __launch_bounds__(256) void spmm_atomic_kernel(
    const float* __restrict__ x,
    const int*   __restrict__ edge_row,
    const int*   __restrict__ edge_col,
    const float* __restrict__ edge_val,
    float*       __restrict__ out,
    int n_edges)
{
    const int gtid = blockIdx.x * blockDim.x + threadIdx.x;
    const int wave = gtid >> 6;
    const int lane = threadIdx.x & 63;
    if (wave >= n_edges) return;
    const int   r = edge_row[wave];
    const int   c = edge_col[wave];
    const float v = edge_val[wave];
    atomicAdd(&out[(size_t)r * D + lane], v * x[(size_t)c * D + lane]);
}

// ---------------- K1: per-block bin counts (LDS hist, coalesced write, NO global atomics) ----
__global__ __launch_bounds__(256) void count_kernel(
    const int* __restrict__ rows, int* __restrict__ counts,
    int n_edges, int nb)
{
    __shared__ int cnt[NB_MAX];
    const int t = threadIdx.x, blk = blockIdx.x;
    for (int i = t; i < nb; i += 256) cnt[i] = 0;
    __syncthreads();
    for (int i = blk * 256 + t; i < n_edges; i += NBLK * 256)
        atomicAdd(&cnt[rows[i] >> 7], 1);          // LDS atomic
    __syncthreads();
    for (int i = t; i < nb; i += 256) counts[blk * nb + i] = cnt[i];
}

// ---------------- K2: per-bin exclusive scan over the NBLK blocks ----------------
// counts[blk][bin] -> cursorbase (in place, exclusive within bin); binsum[bin]
__global__ __launch_bounds__(NBLK) void scan_blocks_kernel(
    int* __restrict__ counts, int* __restrict__ binsum, int nb)
{
    __shared__ int s[NBLK];
    const int b = blockIdx.x, t = threadIdx.x;
    const int mine = counts[t * nb + b];
    s[t] = mine;
    for (int off = 1; off < NBLK; off <<= 1) {
        __syncthreads();
        int v = (t >= off) ? s[t - off] : 0;
        __syncthreads();
        s[t] += v;
    }
    counts[t * nb + b] = s[t] - mine;       // exclusive within bin
    if (t == NBLK - 1) binsum[b] = s[t];
}

// ---------------- K3: exclusive scan over bins -> binbase[nb+1] ----------------
__global__ __launch_bounds__(1024) void scan_bins_kernel(
    const int* __restrict__ binsum, int* __restrict__ binbase, int nb)
{
    __shared__ int s[1024];
    const int t = threadIdx.x;
    const int mine = (t < nb) ? binsum[t] : 0;
    s[t] = mine;
    for (int off = 1; off < 1024; off <<= 1) {
        __syncthreads();
        int v = (t >= off) ? s[t - off] : 0;
        __syncthreads();
        s[t] += v;
    }
    if (t < nb) binbase[t] = s[t] - mine;
    if (t == nb - 1) binbase[nb] = s[t];
}

// ---------------- K4: scatter into PRIVATE per-(block,bin) ranges ----------------
// Same grid/blockDim/loop as K1 -> identical edge assignment -> counts match.
// rec = [ val:f32 (hi32) | localrow:bits17-23 | col:bits0-16 (lo32) ]
// No global atomics; each range has a single writer -> L2 merges the 8B stores.
__global__ __launch_bounds__(256) void scatter_kernel(
    const int* __restrict__ rows, const int* __restrict__ cols,
    const float* __restrict__ vals,
    const int* __restrict__ cursorbase, const int* __restrict__ binbase,
    ull* __restrict__ recs, int n_edges, int nb)
{
    __shared__ int cur[NB_MAX];
    const int t = threadIdx.x, blk = blockIdx.x;
    for (int i = t; i < nb; i += 256)
        cur[i] = binbase[i] + cursorbase[blk * nb + i];
    __syncthreads();
    for (int i = blk * 256 + t; i < n_edges; i += NBLK * 256) {
        const int r = rows[i];
        const unsigned lo = ((unsigned)(r & (RB - 1)) << 17) | (unsigned)cols[i];
        const int pos = atomicAdd(&cur[r >> 7], 1);   // LDS atomic
        recs[pos] = ((ull)__float_as_uint(vals[i]) << 32) | (ull)lo;
    }
}

// ---------------- K5: in-place per-bin sort to exact row order + row offsets ----------------
__global__ __launch_bounds__(256) void binsort_kernel(
    ull* __restrict__ recs, const int* __restrict__ binbase,
    int* __restrict__ offsets_row, int* __restrict__ flags,
    int nb, int n_nodes)
{
    __shared__ ull stage[CAP];
    __shared__ int cnt[RB], sc[RB], cur[RB];
    const int b = blockIdx.x, t = threadIdx.x;
    const int s0 = binbase[b], s1 = binbase[b + 1], len = s1 - s0;

    if (len > CAP) { if (t == 0) flags[b] = 1; return; }   // uniform-block early exit

    for (int i = t; i < RB; i += 256) cnt[i] = 0;
    __syncthreads();

    // stage + local row histogram
    for (int i = t; i < len; i += 256) {
        const ull rr = recs[s0 + i];
        stage[i] = rr;
        atomicAdd(&cnt[(int)((rr >> 17) & (RB - 1))], 1);
    }
    __syncthreads();

    // inclusive scan of cnt[128] (all 256 threads hit barriers)
    if (t < RB) sc[t] = cnt[t];
    for (int off = 1; off < RB; off <<= 1) {
        __syncthreads();
        int v = (t < RB && t >= off) ? sc[t - off] : 0;
        __syncthreads();
        if (t < RB) sc[t] += v;
    }
    __syncthreads();

    if (t < RB) cur[t] = sc[t] - cnt[t];                   // exclusive
    // emit global row offsets (entry RB duplicates next bin's base — same value)
    if (t <= RB) {
        const int r = b * RB + t;
        if (r <= n_nodes)
            offsets_row[r] = s0 + ((t == RB) ? len : (sc[t] - cnt[t]));
    }
    __syncthreads();

    // permute in place (writes stay inside this block's 33 KB segment -> L2-local)
    for (int i = t; i < len; i += 256) {
        const ull rr = stage[i];
        const int p = atomicAdd(&cur[(int)((rr >> 17) & (RB - 1))], 1);
        recs[s0 + p] = rr;
    }
}

// ---------------- K6: CSR SpMM, one wave per row, lane = feature ----------------
__global__ __launch_bounds__(256) void spmm_csr_kernel(
    const float* __restrict__ x,
    const int*   __restrict__ offsets_row,
    const int*   __restrict__ binbase,
    const ull*   __restrict__ recs,
    const int*   __restrict__ flags,
    float*       __restrict__ out,
    int n_nodes)
{
    const int row  = blockIdx.x * 4 + (threadIdx.x >> 6);
    const int lane = threadIdx.x & 63;
    if (row >= n_nodes) return;

    float acc = 0.f;
    const int b = row >> 7;

    if (__builtin_expect(flags[b], 0)) {
        // bin left unsorted: scan whole bin, filter my row
        const int s  = binbase[b];
        const int e  = binbase[b + 1];
        const int lr = row & (RB - 1);
        for (int j = s; j < e; ++j) {
            const ull rec = recs[j];
            if ((int)((rec >> 17) & (RB - 1)) == lr) {
                const int   c = (int)((unsigned)rec & 0x1FFFF);
                const float v = __uint_as_float((unsigned)(rec >> 32));
                acc += v * x[(size_t)c * D + lane];
            }
        }
    } else {
        const int s = offsets_row[row];
        const int e = offsets_row[row + 1];
        int j = s;
        for (; j + 8 <= e; j += 8) {
            float vv[8], xv[8];
            #pragma unroll
            for (int k = 0; k < 8; ++k) {
                const ull rec = recs[j + k];
                vv[k] = __uint_as_float((unsigned)(rec >> 32));
                const int c = (int)((unsigned)rec & 0x1FFFF);
                xv[k] = x[(size_t)c * D + lane];
            }
            #pragma unroll
            for (int k = 0; k < 8; ++k) acc += vv[k] * xv[k];
        }
        for (; j < e; ++j) {
            const ull rec = recs[j];
            const float v = __uint_as_float((unsigned)(rec >> 32));
            const int   c = (int)((unsigned)rec & 0x1FFFF);
            acc += v * x[(size_t)c * D + lane];
        }
    }
    out[(size_t)row * D + lane] = acc;
}

static inline size_t align16(size_t v) { return (v + 15) & ~(size_t)15; }

extern "C" void kernel_launch(void* const* d_in, const int* in_sizes, int n_in,
                              void* d_out, int out_size, void* d_ws, size_t ws_size,
                              hipStream_t stream)
{
    // setup_inputs order: t, x, edge_row, edge_col, edge_val
    const float* x        = (const float*)d_in[1];
    const int*   edge_row = (const int*)d_in[2];
    const int*   edge_col = (const int*)d_in[3];
    const float* edge_val = (const float*)d_in[4];
    float*       out      = (float*)d_out;

    const int n_edges = in_sizes[2];
    const int n_nodes = out_size / D;
    const int nb      = (n_nodes + RB - 1) / RB;

    // workspace carve
    const size_t off_recs    = 0;                                              // n_edges * 8
    const size_t off_counts  = align16(off_recs + (size_t)n_edges * 8);        // NBLK*nb ints
    const size_t off_binsum  = align16(off_counts + (size_t)NBLK * nb * 4);    // nb ints
    const size_t off_binbase = align16(off_binsum + (size_t)nb * 4);           // nb+1 ints
    const size_t off_rowoffs = align16(off_binbase + (size_t)(nb + 1) * 4);    // n_nodes+1 ints
    const size_t off_flags   = align16(off_rowoffs + (size_t)(n_nodes + 1) * 4); // nb ints
    const size_t ws_needed   = off_flags + (size_t)nb * 4;

    if (ws_size < ws_needed || nb > NB_MAX || n_nodes > (1 << 17)) {
        hipMemsetAsync(out, 0, (size_t)out_size * sizeof(float), stream);
        const int n_blocks = (n_edges + 3) / 4;
        spmm_atomic_kernel<<<n_blocks, 256, 0, stream>>>(
            x, edge_row, edge_col, edge_val, out, n_edges);
        return;
    }

    char* ws = (char*)d_ws;
    ull*  recs        = (ull*)(ws + off_recs);
    int*  counts      = (int*)(ws + off_counts);   // becomes cursorbase after K2
    int*  binsum      = (int*)(ws + off_binsum);
    int*  binbase     = (int*)(ws + off_binbase);
    int*  offsets_row = (int*)(ws + off_rowoffs);
    int*  flags       = (int*)(ws + off_flags);

    hipMemsetAsync(flags, 0, (size_t)nb * sizeof(int), stream);

    // K1: per-block bin counts
    count_kernel<<<NBLK, 256, 0, stream>>>(edge_row, counts, n_edges, nb);
    // K2: per-bin scan over blocks -> private ranges
    scan_blocks_kernel<<<nb, NBLK, 0, stream>>>(counts, binsum, nb);
    // K3: bin bases
    scan_bins_kernel<<<1, 1024, 0, stream>>>(binsum, binbase, nb);
    // K4: atomic-free scatter into private contiguous ranges
    scatter_kernel<<<NBLK, 256, 0, stream>>>(edge_row, edge_col, edge_val,
                                             counts, binbase, recs, n_edges, nb);
    // K5: per-bin LDS sort to exact row order + row offsets
    binsort_kernel<<<nb, 256, 0, stream>>>(recs, binbase, offsets_row, flags,
                                           nb, n_nodes);
    // K6: CSR SpMM, one wave per row
    spmm_csr_kernel<<<(n_nodes + 3) / 4, 256, 0, stream>>>(
        x, offsets_row, binbase, recs, flags, out, n_nodes);
}